// Round 16
// baseline (39.271 us; speedup 1.0000x reference)
//
#include <hip/hip_runtime.h>

#define BATCH 16
#define NPTS 4096
#define TOTN (BATCH * NPTS)   // 65536
#define MH 8                  // m-chunks per batch
#define MC (NPTS / MH)        // 512 m per block

typedef _Float16 f16;
typedef __attribute__((ext_vector_type(8))) _Float16 f16x8;
typedef __attribute__((ext_vector_type(16))) float f32x16;

__device__ __forceinline__ unsigned pk(f16 a, f16 b) {
    union { f16 h[2]; unsigned u; } t;
    t.h[0] = a; t.h[1] = b;   // h[0] -> low 16 bits = even k slot
    return t.u;
}

__device__ __forceinline__ float min3f(float a, float b, float c) {
    return fminf(fminf(a, b), c);   // clang fuses to v_min3_f32
}

// Min over the 16 C/D regs (rows of one 32-col tile) then into acc: 8x min3.
__device__ __forceinline__ float treemin(const f32x16& d, float acc) {
    float t0 = min3f(d[0], d[1], d[2]);
    float t1 = min3f(d[3], d[4], d[5]);
    float t2 = min3f(d[6], d[7], d[8]);
    float t3 = min3f(d[9], d[10], d[11]);
    float t4 = min3f(d[12], d[13], d[14]);
    float u0 = min3f(t0, t1, t2);
    float u1 = min3f(t3, t4, d[15]);
    return min3f(acc, u0, u1);
}

// MEASUREMENT ROUND: identical kernels to R15; chamfer launched 3x to expose
// its marginal duration through total dur_us (writes are idempotent).
__global__ __launch_bounds__(256, 6) void chamfer_mfma_kernel(
    const float* __restrict__ xyz, float* __restrict__ partials) {
    __shared__ uint4 T0[MC];   // A-frag k0..7  per m (8 KB)
    __shared__ uint4 T1[MC];   // A-frag k8..15 per m (8 KB)

    const int tid = threadIdx.x;
    const int lane = tid & 63;
    const int wid = tid >> 6;
    const int lm = lane & 31;
    const int kh = lane >> 5;          // which k-half this lane supplies

    const int mh = blockIdx.x & 7;
    const int nsup = (blockIdx.x >> 3) & 15;
    const int b = blockIdx.x >> 7;
    const float* base = xyz + (size_t)b * 3 * NPTS;

    // Stage expanded A-side fragments for this block's 512 m.
    const int m0 = mh * MC;
    for (int i = tid; i < MC; i += 256) {
        int mg = m0 + i;
        float x = base[mg], y = base[NPTS + mg], z = base[2 * NPTS + mg];
        float cx = -2.f * x, cy = -2.f * y, cz = -2.f * z;
        float b2 = fmaf(x, x, fmaf(y, y, z * z));
        f16 cxh = (f16)cx, cxl = (f16)(cx - (float)cxh);
        f16 cyh = (f16)cy, cyl = (f16)(cy - (float)cyh);
        f16 czh = (f16)cz, czl = (f16)(cz - (float)czh);
        f16 b2h = (f16)b2, b2l = (f16)(b2 - (float)b2h);
        T0[i] = make_uint4(pk(cxh, cxh), pk(cxl, cyh), pk(cyh, cyl), pk(czh, czh));
        T1[i] = make_uint4(pk(czl, b2h), pk(b2l, (f16)0.f), 0u, 0u);
    }
    __syncthreads();

    // B-side fragments for this wave's two 32-n tiles.
    const int n0 = nsup * 256 + wid * 64;
    f16x8 Bf[2];
#pragma unroll
    for (int tile = 0; tile < 2; ++tile) {
        int n = n0 + tile * 32 + lm;
        float ax = -base[n];               // mirror across yz-plane
        float ay = base[NPTS + n];
        float az = base[2 * NPTS + n];
        f16 axh = (f16)ax, axl = (f16)(ax - (float)axh);
        f16 ayh = (f16)ay, ayl = (f16)(ay - (float)ayh);
        f16 azh = (f16)az, azl = (f16)(az - (float)azh);
        union { unsigned u[4]; f16x8 v; } B;
        if (kh == 0) {
            B.u[0] = pk(axh, axl); B.u[1] = pk(axh, ayh);
            B.u[2] = pk(ayl, ayh); B.u[3] = pk(azh, azl);
        } else {
            B.u[0] = pk(azh, (f16)1.f); B.u[1] = pk((f16)1.f, (f16)0.f);
            B.u[2] = 0u; B.u[3] = 0u;
        }
        Bf[tile] = B.v;
    }

    const uint4* Ab = kh ? T1 : T0;    // uniform instruction, per-lane base
    float acc0 = 1e30f, acc1 = 1e30f;
    const f32x16 zero = {};

#pragma unroll 2
    for (int t = 0; t < MC / 32; ++t) {
        union { uint4 q; f16x8 v; } A;
        A.q = Ab[t * 32 + lm];         // row m = t*32 + lm, this lane's k-half
        f32x16 d0 = __builtin_amdgcn_mfma_f32_32x32x16_f16(A.v, Bf[0], zero, 0, 0, 0);
        f32x16 d1 = __builtin_amdgcn_mfma_f32_32x32x16_f16(A.v, Bf[1], zero, 0, 0, 0);
        acc0 = treemin(d0, acc0);
        acc1 = treemin(d1, acc1);
    }

    // Combine row-halves (lane vs lane^32 hold complementary rows of each col).
    acc0 = fminf(acc0, __shfl_xor(acc0, 32, 64));
    acc1 = fminf(acc1, __shfl_xor(acc1, 32, 64));

    if (lane < 32) {
        float* dst = partials + (size_t)mh * TOTN + b * NPTS + n0 + lm;
        dst[0] = acc0;
        dst[32] = acc1;
    }
}

// Pass 2: per n, min over MH chunks, add |a_n|^2, block-sum 256 n's.
__global__ __launch_bounds__(256) void combine_kernel(
    const float* __restrict__ xyz, const float* __restrict__ partials,
    float* __restrict__ blocksums) {
    __shared__ float red[4];
    const int n = blockIdx.x * 256 + threadIdx.x;   // 0..TOTN-1
    float v = partials[n];
#pragma unroll
    for (int s = 1; s < MH; ++s) v = fminf(v, partials[(size_t)s * TOTN + n]);

    const int b = n >> 12;
    const int i = n & (NPTS - 1);
    const float* base = xyz + (size_t)b * 3 * NPTS;
    float x = base[i], y = base[NPTS + i], z = base[2 * NPTS + i];
    float sum = v + fmaf(x, x, fmaf(y, y, z * z));

#pragma unroll
    for (int off = 32; off; off >>= 1) sum += __shfl_down(sum, off, 64);
    if ((threadIdx.x & 63) == 0) red[threadIdx.x >> 6] = sum;
    __syncthreads();
    if (threadIdx.x == 0)
        blocksums[blockIdx.x] = (red[0] + red[1]) + (red[2] + red[3]);
}

// Pass 3: 256 block sums -> scalar loss.
__global__ __launch_bounds__(256) void final_kernel(
    const float* __restrict__ blocksums, float* __restrict__ out) {
    __shared__ float red[4];
    float v = blocksums[threadIdx.x];
#pragma unroll
    for (int off = 32; off; off >>= 1) v += __shfl_down(v, off, 64);
    if ((threadIdx.x & 63) == 0) red[threadIdx.x >> 6] = v;
    __syncthreads();
    if (threadIdx.x == 0)
        out[0] = ((red[0] + red[1]) + (red[2] + red[3])) * (2.0f / (float)TOTN);
}

extern "C" void kernel_launch(void* const* d_in, const int* in_sizes, int n_in,
                              void* d_out, int out_size, void* d_ws, size_t ws_size,
                              hipStream_t stream) {
    const float* xyz = (const float*)d_in[0];
    float* out = (float*)d_out;
    float* partials = (float*)d_ws;                    // MH*TOTN floats (2 MB)
    float* blocksums = partials + (size_t)MH * TOTN;   // +256 floats

    // PROBE: chamfer launched 3x (idempotent). Delta vs R15 total / 2 =
    // chamfer_dur + launch-boundary cost.
    chamfer_mfma_kernel<<<BATCH * 16 * MH, 256, 0, stream>>>(xyz, partials);
    chamfer_mfma_kernel<<<BATCH * 16 * MH, 256, 0, stream>>>(xyz, partials);
    chamfer_mfma_kernel<<<BATCH * 16 * MH, 256, 0, stream>>>(xyz, partials);
    combine_kernel<<<TOTN / 256, 256, 0, stream>>>(xyz, partials, blocksums);
    final_kernel<<<1, 256, 0, stream>>>(blocksums, out);
}

// Round 17
// 19.494 us; speedup vs baseline: 2.0145x; 2.0145x over previous
//
#include <hip/hip_runtime.h>

#define BATCH 16
#define NPTS 4096
#define TOTN (BATCH * NPTS)   // 65536
#define MH 8                  // m-chunks per batch
#define MC (NPTS / MH)        // 512 m per block

typedef _Float16 f16;
typedef __attribute__((ext_vector_type(8))) _Float16 f16x8;
typedef __attribute__((ext_vector_type(16))) float f32x16;

__device__ __forceinline__ unsigned pk(f16 a, f16 b) {
    union { f16 h[2]; unsigned u; } t;
    t.h[0] = a; t.h[1] = b;   // h[0] -> low 16 bits = even k slot
    return t.u;
}

__device__ __forceinline__ float min3f(float a, float b, float c) {
    return fminf(fminf(a, b), c);   // clang fuses to v_min3_f32
}

// Min over the 16 C/D regs (rows of one 32-col tile) then into acc: 8x min3.
__device__ __forceinline__ float treemin(const f32x16& d, float acc) {
    float t0 = min3f(d[0], d[1], d[2]);
    float t1 = min3f(d[3], d[4], d[5]);
    float t2 = min3f(d[6], d[7], d[8]);
    float t3 = min3f(d[9], d[10], d[11]);
    float t4 = min3f(d[12], d[13], d[14]);
    float u0 = min3f(t0, t1, t2);
    float u1 = min3f(t3, t4, d[15]);
    return min3f(acc, u0, u1);
}

// Grid = BATCH * 16 nsup * MH = 2048 blocks, (256,4): 128-reg cap, no spills.
// Wave owns 64 n = 2 column-tiles of 32; m-loop unrolled 4x so 4 ds_reads +
// 4 MFMA pairs are in flight (hide MFMA->treemin dependency latency).
__global__ __launch_bounds__(256, 4) void chamfer_mfma_kernel(
    const float* __restrict__ xyz, float* __restrict__ partials) {
    __shared__ uint4 T0[MC];   // A-frag k0..7  per m (8 KB)
    __shared__ uint4 T1[MC];   // A-frag k8..15 per m (8 KB)

    const int tid = threadIdx.x;
    const int lane = tid & 63;
    const int wid = tid >> 6;
    const int lm = lane & 31;
    const int kh = lane >> 5;          // which k-half this lane supplies

    const int mh = blockIdx.x & 7;
    const int nsup = (blockIdx.x >> 3) & 15;
    const int b = blockIdx.x >> 7;
    const float* base = xyz + (size_t)b * 3 * NPTS;

    // Stage expanded A-side fragments for this block's 512 m.
    const int m0 = mh * MC;
    for (int i = tid; i < MC; i += 256) {
        int mg = m0 + i;
        float x = base[mg], y = base[NPTS + mg], z = base[2 * NPTS + mg];
        float cx = -2.f * x, cy = -2.f * y, cz = -2.f * z;
        float b2 = fmaf(x, x, fmaf(y, y, z * z));
        f16 cxh = (f16)cx, cxl = (f16)(cx - (float)cxh);
        f16 cyh = (f16)cy, cyl = (f16)(cy - (float)cyh);
        f16 czh = (f16)cz, czl = (f16)(cz - (float)czh);
        f16 b2h = (f16)b2, b2l = (f16)(b2 - (float)b2h);
        T0[i] = make_uint4(pk(cxh, cxh), pk(cxl, cyh), pk(cyh, cyl), pk(czh, czh));
        T1[i] = make_uint4(pk(czl, b2h), pk(b2l, (f16)0.f), 0u, 0u);
    }
    __syncthreads();

    // B-side fragments for this wave's two 32-n tiles.
    const int n0 = nsup * 256 + wid * 64;
    f16x8 Bf[2];
#pragma unroll
    for (int tile = 0; tile < 2; ++tile) {
        int n = n0 + tile * 32 + lm;
        float ax = -base[n];               // mirror across yz-plane
        float ay = base[NPTS + n];
        float az = base[2 * NPTS + n];
        f16 axh = (f16)ax, axl = (f16)(ax - (float)axh);
        f16 ayh = (f16)ay, ayl = (f16)(ay - (float)ayh);
        f16 azh = (f16)az, azl = (f16)(az - (float)azh);
        union { unsigned u[4]; f16x8 v; } B;
        if (kh == 0) {
            B.u[0] = pk(axh, axl); B.u[1] = pk(axh, ayh);
            B.u[2] = pk(ayl, ayh); B.u[3] = pk(azh, azl);
        } else {
            B.u[0] = pk(azh, (f16)1.f); B.u[1] = pk((f16)1.f, (f16)0.f);
            B.u[2] = 0u; B.u[3] = 0u;
        }
        Bf[tile] = B.v;
    }

    const uint4* Ab = kh ? T1 : T0;    // uniform instruction, per-lane base
    float acc0 = 1e30f, acc1 = 1e30f;
    const f32x16 zero = {};

#pragma unroll 4
    for (int t = 0; t < MC / 32; ++t) {
        union { uint4 q; f16x8 v; } A;
        A.q = Ab[t * 32 + lm];         // row m = t*32 + lm, this lane's k-half
        f32x16 d0 = __builtin_amdgcn_mfma_f32_32x32x16_f16(A.v, Bf[0], zero, 0, 0, 0);
        f32x16 d1 = __builtin_amdgcn_mfma_f32_32x32x16_f16(A.v, Bf[1], zero, 0, 0, 0);
        acc0 = treemin(d0, acc0);
        acc1 = treemin(d1, acc1);
    }

    // Combine row-halves (lane vs lane^32 hold complementary rows of each col).
    acc0 = fminf(acc0, __shfl_xor(acc0, 32, 64));
    acc1 = fminf(acc1, __shfl_xor(acc1, 32, 64));

    // Full-wave store: lanes 0-31 write acc0 cols, lanes 32-63 write acc1 cols.
    float* dst = partials + (size_t)mh * TOTN + b * NPTS + n0;
    dst[kh * 32 + lm] = kh ? acc1 : acc0;
}

// Pass 2: 4 n per thread via float4; min over MH chunks, add |a_n|^2,
// block-sum 1024 n's. Grid = 64 blocks.
__global__ __launch_bounds__(256) void combine_kernel(
    const float* __restrict__ xyz, const float* __restrict__ partials,
    float* __restrict__ blocksums) {
    __shared__ float red[4];
    const int n0 = (blockIdx.x * 256 + threadIdx.x) * 4;   // 0..TOTN-4
    float4 v = *reinterpret_cast<const float4*>(&partials[n0]);
#pragma unroll
    for (int s = 1; s < MH; ++s) {
        float4 p = *reinterpret_cast<const float4*>(&partials[(size_t)s * TOTN + n0]);
        v.x = fminf(v.x, p.x); v.y = fminf(v.y, p.y);
        v.z = fminf(v.z, p.z); v.w = fminf(v.w, p.w);
    }

    const int b = n0 >> 12;
    const int i = n0 & (NPTS - 1);
    const float* base = xyz + (size_t)b * 3 * NPTS;
    float4 xv = *reinterpret_cast<const float4*>(&base[i]);
    float4 yv = *reinterpret_cast<const float4*>(&base[NPTS + i]);
    float4 zv = *reinterpret_cast<const float4*>(&base[2 * NPTS + i]);

    float s0 = v.x + fmaf(xv.x, xv.x, fmaf(yv.x, yv.x, zv.x * zv.x));
    float s1 = v.y + fmaf(xv.y, xv.y, fmaf(yv.y, yv.y, zv.y * zv.y));
    float s2 = v.z + fmaf(xv.z, xv.z, fmaf(yv.z, yv.z, zv.z * zv.z));
    float s3 = v.w + fmaf(xv.w, xv.w, fmaf(yv.w, yv.w, zv.w * zv.w));
    float sum = (s0 + s1) + (s2 + s3);

#pragma unroll
    for (int off = 32; off; off >>= 1) sum += __shfl_down(sum, off, 64);
    if ((threadIdx.x & 63) == 0) red[threadIdx.x >> 6] = sum;
    __syncthreads();
    if (threadIdx.x == 0)
        blocksums[blockIdx.x] = (red[0] + red[1]) + (red[2] + red[3]);
}

// Pass 3: one wave reduces the 64 block sums -> scalar loss.
__global__ __launch_bounds__(64) void final_kernel(
    const float* __restrict__ blocksums, float* __restrict__ out) {
    float v = blocksums[threadIdx.x];
#pragma unroll
    for (int off = 32; off; off >>= 1) v += __shfl_down(v, off, 64);
    if (threadIdx.x == 0) out[0] = v * (2.0f / (float)TOTN);
}

extern "C" void kernel_launch(void* const* d_in, const int* in_sizes, int n_in,
                              void* d_out, int out_size, void* d_ws, size_t ws_size,
                              hipStream_t stream) {
    const float* xyz = (const float*)d_in[0];
    float* out = (float*)d_out;
    float* partials = (float*)d_ws;                    // MH*TOTN floats (2 MB)
    float* blocksums = partials + (size_t)MH * TOTN;   // +64 floats

    chamfer_mfma_kernel<<<BATCH * 16 * MH, 256, 0, stream>>>(xyz, partials);
    combine_kernel<<<TOTN / 1024, 256, 0, stream>>>(xyz, partials, blocksums);
    final_kernel<<<1, 64, 0, stream>>>(blocksums, out);
}

// Round 18
// 17.762 us; speedup vs baseline: 2.2110x; 1.0975x over previous
//
#include <hip/hip_runtime.h>

#define BATCH 16
#define NPTS 4096
#define TOTN (BATCH * NPTS)   // 65536
#define MH 4                  // m-chunks per batch
#define MC (NPTS / MH)        // 1024 m per block

typedef _Float16 f16;
typedef __attribute__((ext_vector_type(8))) _Float16 f16x8;
typedef __attribute__((ext_vector_type(16))) float f32x16;

__device__ __forceinline__ unsigned pk(f16 a, f16 b) {
    union { f16 h[2]; unsigned u; } t;
    t.h[0] = a; t.h[1] = b;   // h[0] -> low 16 bits = even k slot
    return t.u;
}

__device__ __forceinline__ float min3f(float a, float b, float c) {
    return fminf(fminf(a, b), c);   // clang fuses to v_min3_f32
}

// Min over the 16 C/D regs (rows of one 32-col tile) then into acc: 8x min3.
__device__ __forceinline__ float treemin(const f32x16& d, float acc) {
    float t0 = min3f(d[0], d[1], d[2]);
    float t1 = min3f(d[3], d[4], d[5]);
    float t2 = min3f(d[6], d[7], d[8]);
    float t3 = min3f(d[9], d[10], d[11]);
    float t4 = min3f(d[12], d[13], d[14]);
    float u0 = min3f(t0, t1, t2);
    float u1 = min3f(t3, t4, d[15]);
    return min3f(acc, u0, u1);
}

// Grid = BATCH * 16 nsup * MH = 1024 blocks, (256,4), 32 KB LDS -> 4 blocks/CU.
// Wave owns 64 n = 2 column-tiles of 32; 64 m-iters per block (MH=4 amortizes
// the B-frag/staging prologue 4x better than MH=8). Also zeroes out[0] for
// the atomic tail in pass 2 (stream order guarantees visibility).
__global__ __launch_bounds__(256, 4) void chamfer_mfma_kernel(
    const float* __restrict__ xyz, float* __restrict__ partials,
    float* __restrict__ out) {
    __shared__ uint4 T0[MC];   // A-frag k0..7  per m (16 KB)
    __shared__ uint4 T1[MC];   // A-frag k8..15 per m (16 KB)

    const int tid = threadIdx.x;
    if (blockIdx.x == 0 && tid == 0) out[0] = 0.0f;   // reset accumulator

    const int lane = tid & 63;
    const int wid = tid >> 6;
    const int lm = lane & 31;
    const int kh = lane >> 5;          // which k-half this lane supplies

    const int mh = blockIdx.x & (MH - 1);
    const int nsup = (blockIdx.x >> 2) & 15;
    const int b = blockIdx.x >> 6;
    const float* base = xyz + (size_t)b * 3 * NPTS;

    // Stage expanded A-side fragments for this block's 1024 m.
    const int m0 = mh * MC;
    for (int i = tid; i < MC; i += 256) {
        int mg = m0 + i;
        float x = base[mg], y = base[NPTS + mg], z = base[2 * NPTS + mg];
        float cx = -2.f * x, cy = -2.f * y, cz = -2.f * z;
        float b2 = fmaf(x, x, fmaf(y, y, z * z));
        f16 cxh = (f16)cx, cxl = (f16)(cx - (float)cxh);
        f16 cyh = (f16)cy, cyl = (f16)(cy - (float)cyh);
        f16 czh = (f16)cz, czl = (f16)(cz - (float)czh);
        f16 b2h = (f16)b2, b2l = (f16)(b2 - (float)b2h);
        T0[i] = make_uint4(pk(cxh, cxh), pk(cxl, cyh), pk(cyh, cyl), pk(czh, czh));
        T1[i] = make_uint4(pk(czl, b2h), pk(b2l, (f16)0.f), 0u, 0u);
    }
    __syncthreads();

    // B-side fragments for this wave's two 32-n tiles.
    const int n0 = nsup * 256 + wid * 64;
    f16x8 Bf[2];
#pragma unroll
    for (int tile = 0; tile < 2; ++tile) {
        int n = n0 + tile * 32 + lm;
        float ax = -base[n];               // mirror across yz-plane
        float ay = base[NPTS + n];
        float az = base[2 * NPTS + n];
        f16 axh = (f16)ax, axl = (f16)(ax - (float)axh);
        f16 ayh = (f16)ay, ayl = (f16)(ay - (float)ayh);
        f16 azh = (f16)az, azl = (f16)(az - (float)azh);
        union { unsigned u[4]; f16x8 v; } B;
        if (kh == 0) {
            B.u[0] = pk(axh, axl); B.u[1] = pk(axh, ayh);
            B.u[2] = pk(ayl, ayh); B.u[3] = pk(azh, azl);
        } else {
            B.u[0] = pk(azh, (f16)1.f); B.u[1] = pk((f16)1.f, (f16)0.f);
            B.u[2] = 0u; B.u[3] = 0u;
        }
        Bf[tile] = B.v;
    }

    const uint4* Ab = kh ? T1 : T0;    // uniform instruction, per-lane base
    float acc0 = 1e30f, acc1 = 1e30f;
    const f32x16 zero = {};

#pragma unroll 4
    for (int t = 0; t < MC / 32; ++t) {
        union { uint4 q; f16x8 v; } A;
        A.q = Ab[t * 32 + lm];         // row m = t*32 + lm, this lane's k-half
        f32x16 d0 = __builtin_amdgcn_mfma_f32_32x32x16_f16(A.v, Bf[0], zero, 0, 0, 0);
        f32x16 d1 = __builtin_amdgcn_mfma_f32_32x32x16_f16(A.v, Bf[1], zero, 0, 0, 0);
        acc0 = treemin(d0, acc0);
        acc1 = treemin(d1, acc1);
    }

    // Combine row-halves (lane vs lane^32 hold complementary rows of each col).
    acc0 = fminf(acc0, __shfl_xor(acc0, 32, 64));
    acc1 = fminf(acc1, __shfl_xor(acc1, 32, 64));

    // Full-wave store: lanes 0-31 write acc0 cols, lanes 32-63 write acc1 cols.
    float* dst = partials + (size_t)mh * TOTN + b * NPTS + n0;
    dst[kh * 32 + lm] = kh ? acc1 : acc0;
}

// Pass 2 (tail): 4 n per thread via float4; min over MH chunks, add |a_n|^2,
// block-sum 1024 n's, one scaled float atomicAdd into out[0] per block.
// No fences/counters: stream order already published partials; the 64 atomics
// are unordered (last-ulp nondeterminism only, far under the 1.37e-3 threshold).
__global__ __launch_bounds__(256) void combine_kernel(
    const float* __restrict__ xyz, const float* __restrict__ partials,
    float* __restrict__ out) {
    __shared__ float red[4];
    const int n0 = (blockIdx.x * 256 + threadIdx.x) * 4;   // 0..TOTN-4
    float4 v = *reinterpret_cast<const float4*>(&partials[n0]);
#pragma unroll
    for (int s = 1; s < MH; ++s) {
        float4 p = *reinterpret_cast<const float4*>(&partials[(size_t)s * TOTN + n0]);
        v.x = fminf(v.x, p.x); v.y = fminf(v.y, p.y);
        v.z = fminf(v.z, p.z); v.w = fminf(v.w, p.w);
    }

    const int b = n0 >> 12;
    const int i = n0 & (NPTS - 1);
    const float* base = xyz + (size_t)b * 3 * NPTS;
    float4 xv = *reinterpret_cast<const float4*>(&base[i]);
    float4 yv = *reinterpret_cast<const float4*>(&base[NPTS + i]);
    float4 zv = *reinterpret_cast<const float4*>(&base[2 * NPTS + i]);

    float s0 = v.x + fmaf(xv.x, xv.x, fmaf(yv.x, yv.x, zv.x * zv.x));
    float s1 = v.y + fmaf(xv.y, xv.y, fmaf(yv.y, yv.y, zv.y * zv.y));
    float s2 = v.z + fmaf(xv.z, xv.z, fmaf(yv.z, yv.z, zv.z * zv.z));
    float s3 = v.w + fmaf(xv.w, xv.w, fmaf(yv.w, yv.w, zv.w * zv.w));
    float sum = (s0 + s1) + (s2 + s3);

#pragma unroll
    for (int off = 32; off; off >>= 1) sum += __shfl_down(sum, off, 64);
    if ((threadIdx.x & 63) == 0) red[threadIdx.x >> 6] = sum;
    __syncthreads();
    if (threadIdx.x == 0) {
        float bs = (red[0] + red[1]) + (red[2] + red[3]);
        atomicAdd(out, bs * (2.0f / (float)TOTN));
    }
}

extern "C" void kernel_launch(void* const* d_in, const int* in_sizes, int n_in,
                              void* d_out, int out_size, void* d_ws, size_t ws_size,
                              hipStream_t stream) {
    const float* xyz = (const float*)d_in[0];
    float* out = (float*)d_out;
    float* partials = (float*)d_ws;                    // MH*TOTN floats (1 MB)

    chamfer_mfma_kernel<<<BATCH * 16 * MH, 256, 0, stream>>>(xyz, partials, out);
    combine_kernel<<<TOTN / 1024, 256, 0, stream>>>(xyz, partials, out);
}